// Round 5
// baseline (135.461 us; speedup 1.0000x reference)
//
#include <hip/hip_runtime.h>
#include <hip/hip_fp16.h>

static constexpr int BASE = 512;

// half-element offsets of each level in the (h,w,16)-layout fp16 pyramid
__constant__ int c_off[8] = {0, 4194304, 5242880, 5505024, 5570560, 5586944, 5591040, 5592064};
// total halves = 5592320 -> 11,184,640 bytes of ws

// ---------------- Kernel A1: transpose (C,512,512) fp32 -> (512,512,C) fp16 ----------------
__global__ void transpose_l0(const float* __restrict__ tex, __half* __restrict__ dst) {
    int pix = blockIdx.x * blockDim.x + threadIdx.x;   // grid sized exactly: 262144 threads
    float v[16];
#pragma unroll
    for (int c = 0; c < 16; ++c) v[c] = tex[c * 262144 + pix];
    __half2 h[8];
#pragma unroll
    for (int i = 0; i < 8; ++i) h[i] = __floats2half2_rn(v[2 * i], v[2 * i + 1]);
    float4* o = (float4*)(dst + (size_t)pix * 16);
    o[0] = *(const float4*)&h[0];
    o[1] = *(const float4*)&h[4];
}

// convert one 32B texel (16 halves) to 16 floats
__device__ inline void load_texel16(const __half* p, float* f) {
    float4 r0 = ((const float4*)p)[0];
    float4 r1 = ((const float4*)p)[1];
    const __half2* h0 = (const __half2*)&r0;
    const __half2* h1 = (const __half2*)&r1;
#pragma unroll
    for (int i = 0; i < 4; ++i) {
        float2 a = __half22float2(h0[i]);
        f[2 * i] = a.x; f[2 * i + 1] = a.y;
        float2 b = __half22float2(h1[i]);
        f[8 + 2 * i] = b.x; f[9 + 2 * i] = b.y;
    }
}

// ---------------- Kernel A2: build levels 1..7 from fp16 L0 ----------------
// Reference resize (align_corners=False, pow2 scale) == 2x2 avg at
// yy=(y<<l)+(1<<(l-1))-1, association: (v00*.5+v10*.5)*.5+(v01*.5+v11*.5)*.5
__global__ void build_levels(const __half* __restrict__ l0, __half* __restrict__ ws) {
    int lev = blockIdx.y + 1;            // 1..7
    int w = BASE >> lev;
    int npix = w * w;
    int pix = blockIdx.x * blockDim.x + threadIdx.x;
    if (pix >= npix) return;
    int y = pix >> (9 - lev);
    int x = pix & (w - 1);
    int xx = (x << lev) + (1 << (lev - 1)) - 1;
    int yy = (y << lev) + (1 << (lev - 1)) - 1;
    const __half* b00 = l0 + (size_t)(yy * 512 + xx) * 16;
    float a[16], b[16], c[16], d[16];
    load_texel16(b00, a);                // (yy  , xx  )
    load_texel16(b00 + 16, b);           // (yy  , xx+1)
    load_texel16(b00 + 512 * 16, c);     // (yy+1, xx  )
    load_texel16(b00 + 512 * 16 + 16, d);// (yy+1, xx+1)
    __half2 r[8];
#pragma unroll
    for (int i = 0; i < 8; ++i) {
        float r0 = (a[2 * i] * 0.5f + c[2 * i] * 0.5f) * 0.5f +
                   (b[2 * i] * 0.5f + d[2 * i] * 0.5f) * 0.5f;
        float r1 = (a[2 * i + 1] * 0.5f + c[2 * i + 1] * 0.5f) * 0.5f +
                   (b[2 * i + 1] * 0.5f + d[2 * i + 1] * 0.5f) * 0.5f;
        r[i] = __floats2half2_rn(r0, r1);
    }
    float4* dst = (float4*)(ws + c_off[lev] + (size_t)pix * 16);
    dst[0] = *(const float4*)&r[0];
    dst[1] = *(const float4*)&r[4];
}

// ---------------- Kernel B: trilinear mip sampling ----------------
// 2 threads per query; thread q handles channels [8q, 8q+8).
// All 8 texel loads (both levels) are issued before any use -> 8-deep MLP.
// Texel = 16 halves = 2 float4s; c_off is in half units -> float4 index =
//   (c_off[l] >> 3) + (y*w + x)*2 + q
__global__ __launch_bounds__(256, 8)
void sample_kernel(const float2* __restrict__ uv, const float* __restrict__ p,
                   const __half* __restrict__ ws, float* __restrict__ out, int N) {
    int tid = blockIdx.x * blockDim.x + threadIdx.x;
    int n = tid >> 1;
    int q = tid & 1;
    if (n >= N) return;

    float2 uvn = uv[n];
    float pp = p[n];
    float gx = 2.0f * uvn.x - 1.0f;
    float gy = 2.0f * uvn.y - 1.0f;

    float lf = pp * 7.0f;
    int l0 = min((int)lf, 7);            // lf >= 0
    int l1 = min(l0 + 1, 7);
    float alpha = lf - (float)l0;

    // ---- address setup for both levels (no loads yet) ----
    int idx[8];        // float4-granule indices into ws
    float wgt[8];      // bilinear*level weight per texel
    int ls2[2] = {l0, l1};
    float lw2[2] = {1.0f - alpha, alpha};
#pragma unroll
    for (int k = 0; k < 2; ++k) {
        int l = ls2[k];
        int w = BASE >> l;
        float wm1 = (float)(w - 1);
        float x = fminf(fmaxf((gx + 1.0f) * 0.5f * wm1, 0.0f), wm1);
        float y = fminf(fmaxf((gy + 1.0f) * 0.5f * wm1, 0.0f), wm1);
        int x0 = min((int)x, w - 1);
        int y0 = min((int)y, w - 1);
        int x1 = min(x0 + 1, w - 1);
        int y1 = min(y0 + 1, w - 1);
        float fx = x - (float)x0;
        float fy = y - (float)y0;
        int base = (c_off[l] >> 3) + q;       // in float4 units
        idx[4 * k + 0] = base + (y0 * w + x0) * 2;
        idx[4 * k + 1] = base + (y0 * w + x1) * 2;
        idx[4 * k + 2] = base + (y1 * w + x0) * 2;
        idx[4 * k + 3] = base + (y1 * w + x1) * 2;
        wgt[4 * k + 0] = (1.0f - fx) * (1.0f - fy) * lw2[k];
        wgt[4 * k + 1] = fx * (1.0f - fy) * lw2[k];
        wgt[4 * k + 2] = (1.0f - fx) * fy * lw2[k];
        wgt[4 * k + 3] = fx * fy * lw2[k];
    }

    // ---- issue all 8 loads ----
    const float4* t = (const float4*)ws;
    float4 r0 = t[idx[0]];
    float4 r1 = t[idx[1]];
    float4 r2 = t[idx[2]];
    float4 r3 = t[idx[3]];
    float4 r4 = t[idx[4]];
    float4 r5 = t[idx[5]];
    float4 r6 = t[idx[6]];
    float4 r7 = t[idx[7]];
    float4 rr[8] = {r0, r1, r2, r3, r4, r5, r6, r7};

    // ---- convert + weighted accumulate ----
    float acc[8];
#pragma unroll
    for (int j = 0; j < 8; ++j) acc[j] = 0.0f;
#pragma unroll
    for (int i = 0; i < 8; ++i) {
        const __half2* h = (const __half2*)&rr[i];
        float wv = wgt[i];
#pragma unroll
        for (int j = 0; j < 4; ++j) {
            float2 a = __half22float2(h[j]);
            acc[2 * j]     += a.x * wv;
            acc[2 * j + 1] += a.y * wv;
        }
    }

    float4* o = (float4*)(out + (size_t)n * 16 + 8 * q);
    o[0] = make_float4(acc[0], acc[1], acc[2], acc[3]);
    o[1] = make_float4(acc[4], acc[5], acc[6], acc[7]);
}

extern "C" void kernel_launch(void* const* d_in, const int* in_sizes, int n_in,
                              void* d_out, int out_size, void* d_ws, size_t ws_size,
                              hipStream_t stream) {
    const float* uv  = (const float*)d_in[0];
    const float* p   = (const float*)d_in[1];
    const float* tex = (const float*)d_in[2];
    float* out = (float*)d_out;
    __half* ws = (__half*)d_ws;
    int N = in_sizes[1];

    // A1: transpose+convert base level into ws (262144 pixels, exact grid)
    transpose_l0<<<262144 / 256, 256, 0, stream>>>(tex, ws);

    // A2: build levels 1..7
    dim3 gA2(256, 7);
    build_levels<<<gA2, 256, 0, stream>>>(ws, ws);

    // B: sample (2 threads per query)
    long long total = (long long)N * 2;
    int blocks = (int)((total + 255) / 256);
    sample_kernel<<<blocks, 256, 0, stream>>>((const float2*)uv, p, ws, out, N);
}

// Round 8
// 128.892 us; speedup vs baseline: 1.0510x; 1.0510x over previous
//
#include <hip/hip_runtime.h>
#include <hip/hip_fp16.h>

static constexpr int BASE = 512;

// half-element offsets of each level in the (h,w,16)-layout fp16 pyramid
__constant__ int c_off[8] = {0, 4194304, 5242880, 5505024, 5570560, 5586944, 5591040, 5592064};
// total halves = 5592320 -> 11,184,640 bytes of ws

// ---------------- Kernel A1: transpose (C,512,512) fp32 -> (512,512,C) fp16 ----------------
__global__ void transpose_l0(const float* __restrict__ tex, __half* __restrict__ dst) {
    int pix = blockIdx.x * blockDim.x + threadIdx.x;   // grid sized exactly: 262144 threads
    float v[16];
#pragma unroll
    for (int c = 0; c < 16; ++c) v[c] = tex[c * 262144 + pix];
    __half2 h[8];
#pragma unroll
    for (int i = 0; i < 8; ++i) h[i] = __floats2half2_rn(v[2 * i], v[2 * i + 1]);
    float4* o = (float4*)(dst + (size_t)pix * 16);
    o[0] = *(const float4*)&h[0];
    o[1] = *(const float4*)&h[4];
}

// convert one 32B texel (16 halves) to 16 floats
__device__ inline void load_texel16(const __half* p, float* f) {
    float4 r0 = ((const float4*)p)[0];
    float4 r1 = ((const float4*)p)[1];
    const __half2* h0 = (const __half2*)&r0;
    const __half2* h1 = (const __half2*)&r1;
#pragma unroll
    for (int i = 0; i < 4; ++i) {
        float2 a = __half22float2(h0[i]);
        f[2 * i] = a.x; f[2 * i + 1] = a.y;
        float2 b = __half22float2(h1[i]);
        f[8 + 2 * i] = b.x; f[9 + 2 * i] = b.y;
    }
}

// ---------------- Kernel A2: build levels 1..7 from fp16 L0 ----------------
// Reference resize (align_corners=False, pow2 scale) == 2x2 avg at
// yy=(y<<l)+(1<<(l-1))-1, association: (v00*.5+v10*.5)*.5+(v01*.5+v11*.5)*.5
__global__ void build_levels(const __half* __restrict__ l0, __half* __restrict__ ws) {
    int lev = blockIdx.y + 1;            // 1..7
    int w = BASE >> lev;
    int npix = w * w;
    int pix = blockIdx.x * blockDim.x + threadIdx.x;
    if (pix >= npix) return;
    int y = pix >> (9 - lev);
    int x = pix & (w - 1);
    int xx = (x << lev) + (1 << (lev - 1)) - 1;
    int yy = (y << lev) + (1 << (lev - 1)) - 1;
    const __half* b00 = l0 + (size_t)(yy * 512 + xx) * 16;
    float a[16], b[16], c[16], d[16];
    load_texel16(b00, a);                // (yy  , xx  )
    load_texel16(b00 + 16, b);           // (yy  , xx+1)
    load_texel16(b00 + 512 * 16, c);     // (yy+1, xx  )
    load_texel16(b00 + 512 * 16 + 16, d);// (yy+1, xx+1)
    __half2 r[8];
#pragma unroll
    for (int i = 0; i < 8; ++i) {
        float r0 = (a[2 * i] * 0.5f + c[2 * i] * 0.5f) * 0.5f +
                   (b[2 * i] * 0.5f + d[2 * i] * 0.5f) * 0.5f;
        float r1 = (a[2 * i + 1] * 0.5f + c[2 * i + 1] * 0.5f) * 0.5f +
                   (b[2 * i + 1] * 0.5f + d[2 * i + 1] * 0.5f) * 0.5f;
        r[i] = __floats2half2_rn(r0, r1);
    }
    float4* dst = (float4*)(ws + c_off[lev] + (size_t)pix * 16);
    dst[0] = *(const float4*)&r[0];
    dst[1] = *(const float4*)&r[4];
}

// ---------------- Kernel B: trilinear mip sampling ----------------
// 2 threads per query; thread q handles channels [8q, 8q+8).
// All 8 texel gathers + the waitcnt live in ONE asm block: compiler must
// materialize all addresses first and cannot hoist consumers above the wait.
__global__ __launch_bounds__(256, 6)
void sample_kernel(const float2* __restrict__ uv, const float* __restrict__ p,
                   const __half* __restrict__ ws, float* __restrict__ out, int N) {
    int tid = blockIdx.x * blockDim.x + threadIdx.x;
    int n = tid >> 1;
    int q = tid & 1;
    if (n >= N) return;

    float2 uvn = uv[n];
    float pp = p[n];
    float gx = 2.0f * uvn.x - 1.0f;
    float gy = 2.0f * uvn.y - 1.0f;

    float lf = pp * 7.0f;
    int l0 = min((int)lf, 7);            // lf >= 0
    int l1 = min(l0 + 1, 7);
    float alpha = lf - (float)l0;

    // ---- address setup for both levels (no loads yet) ----
    int idx[8];        // float4-granule indices into ws
    float wgt[8];      // bilinear*level weight per texel
    int ls2[2] = {l0, l1};
    float lw2[2] = {1.0f - alpha, alpha};
#pragma unroll
    for (int k = 0; k < 2; ++k) {
        int l = ls2[k];
        int w = BASE >> l;
        float wm1 = (float)(w - 1);
        float x = fminf(fmaxf((gx + 1.0f) * 0.5f * wm1, 0.0f), wm1);
        float y = fminf(fmaxf((gy + 1.0f) * 0.5f * wm1, 0.0f), wm1);
        int x0 = min((int)x, w - 1);
        int y0 = min((int)y, w - 1);
        int x1 = min(x0 + 1, w - 1);
        int y1 = min(y0 + 1, w - 1);
        float fx = x - (float)x0;
        float fy = y - (float)y0;
        int base = (c_off[l] >> 3) + q;       // in float4 units (texel = 2 float4s)
        idx[4 * k + 0] = base + (y0 * w + x0) * 2;
        idx[4 * k + 1] = base + (y0 * w + x1) * 2;
        idx[4 * k + 2] = base + (y1 * w + x0) * 2;
        idx[4 * k + 3] = base + (y1 * w + x1) * 2;
        wgt[4 * k + 0] = (1.0f - fx) * (1.0f - fy) * lw2[k];
        wgt[4 * k + 1] = fx * (1.0f - fy) * lw2[k];
        wgt[4 * k + 2] = (1.0f - fx) * fy * lw2[k];
        wgt[4 * k + 3] = fx * fy * lw2[k];
    }

    // ---- issue all 8 loads + wait in a single asm block ----
    const float4* t = (const float4*)ws;
    const float4* p0 = t + idx[0];
    const float4* p1 = t + idx[1];
    const float4* p2 = t + idx[2];
    const float4* p3 = t + idx[3];
    const float4* p4 = t + idx[4];
    const float4* p5 = t + idx[5];
    const float4* p6 = t + idx[6];
    const float4* p7 = t + idx[7];
    float4 r0, r1, r2, r3, r4, r5, r6, r7;
    asm volatile(
        "global_load_dwordx4 %0, %8, off\n\t"
        "global_load_dwordx4 %1, %9, off\n\t"
        "global_load_dwordx4 %2, %10, off\n\t"
        "global_load_dwordx4 %3, %11, off\n\t"
        "global_load_dwordx4 %4, %12, off\n\t"
        "global_load_dwordx4 %5, %13, off\n\t"
        "global_load_dwordx4 %6, %14, off\n\t"
        "global_load_dwordx4 %7, %15, off\n\t"
        "s_waitcnt vmcnt(0)"
        : "=&v"(r0), "=&v"(r1), "=&v"(r2), "=&v"(r3),
          "=&v"(r4), "=&v"(r5), "=&v"(r6), "=&v"(r7)
        : "v"(p0), "v"(p1), "v"(p2), "v"(p3),
          "v"(p4), "v"(p5), "v"(p6), "v"(p7));

    // ---- convert + weighted accumulate ----
    float acc[8];
#pragma unroll
    for (int j = 0; j < 8; ++j) acc[j] = 0.0f;

#define ACCUM(R, I)                                            \
    {                                                          \
        const __half2* h = (const __half2*)&(R);               \
        float wv = wgt[I];                                     \
        _Pragma("unroll")                                      \
        for (int j = 0; j < 4; ++j) {                          \
            float2 a = __half22float2(h[j]);                   \
            acc[2 * j]     += a.x * wv;                        \
            acc[2 * j + 1] += a.y * wv;                        \
        }                                                      \
    }
    ACCUM(r0, 0) ACCUM(r1, 1) ACCUM(r2, 2) ACCUM(r3, 3)
    ACCUM(r4, 4) ACCUM(r5, 5) ACCUM(r6, 6) ACCUM(r7, 7)
#undef ACCUM

    float4* o = (float4*)(out + (size_t)n * 16 + 8 * q);
    o[0] = make_float4(acc[0], acc[1], acc[2], acc[3]);
    o[1] = make_float4(acc[4], acc[5], acc[6], acc[7]);
}

extern "C" void kernel_launch(void* const* d_in, const int* in_sizes, int n_in,
                              void* d_out, int out_size, void* d_ws, size_t ws_size,
                              hipStream_t stream) {
    const float* uv  = (const float*)d_in[0];
    const float* p   = (const float*)d_in[1];
    const float* tex = (const float*)d_in[2];
    float* out = (float*)d_out;
    __half* ws = (__half*)d_ws;
    int N = in_sizes[1];

    // A1: transpose+convert base level into ws (262144 pixels, exact grid)
    transpose_l0<<<262144 / 256, 256, 0, stream>>>(tex, ws);

    // A2: build levels 1..7
    dim3 gA2(256, 7);
    build_levels<<<gA2, 256, 0, stream>>>(ws, ws);

    // B: sample (2 threads per query)
    long long total = (long long)N * 2;
    int blocks = (int)((total + 255) / 256);
    sample_kernel<<<blocks, 256, 0, stream>>>((const float2*)uv, p, ws, out, N);
}